// Round 1
// baseline (178.316 us; speedup 1.0000x reference)
//
#include <hip/hip_runtime.h>

typedef unsigned short u16;
typedef unsigned int u32;
typedef short short8 __attribute__((ext_vector_type(8)));
typedef short short4v __attribute__((ext_vector_type(4)));
typedef float f32x4 __attribute__((ext_vector_type(4)));

#define EPS 1e-3f
#define C1F 0.18033688011112042f   // 0.125 * log2(e), folded into wk/bk in prep

#if defined(__HIP_DEVICE_COMPILE__)
#define MFMA16(a, b, c) __builtin_amdgcn_mfma_f32_16x16x16bf16_1k(a, b, c, 0, 0, 0)
#define EXP2F(x) __builtin_amdgcn_exp2f(x)
#else
#define MFMA16(a, b, c) (c)
#define EXP2F(x) exp2f(x)
#endif

static __device__ __forceinline__ u16 f2bf(float f) {
    u32 u = __float_as_uint(f);
    u += 0x7fffu + ((u >> 16) & 1u);   // round-to-nearest-even
    return (u16)(u >> 16);
}
static __device__ __forceinline__ float bf2f(u16 v) {
    u32 u = (u32)v << 16;
    return __uint_as_float(u);
}
// truncation pack (P in [0,1], trunc error <0.4% rel — fine for softmax weights)
static __device__ __forceinline__ u32 pack_bf2_trunc(float a, float b) {
    return __builtin_amdgcn_perm(__float_as_uint(b), __float_as_uint(a), 0x07060302u);
}
static __device__ __forceinline__ void async_cp16(const void* g, void* l) {
    __builtin_amdgcn_global_load_lds(
        (const __attribute__((address_space(1))) unsigned int*)g,
        (__attribute__((address_space(3))) unsigned int*)l, 16, 0, 0);
}

// ---------------------------------------------------------------------------
// prep + bn1 merged. Blocks [0,2048): bn1(x)->h bf16. Blocks [2048,5125):
// weight transposes (coalesced reads), bqkv, bn sc/sh.
// ---------------------------------------------------------------------------
__global__ void prep_bn1_kernel(const float* __restrict__ x,
                            const float* __restrict__ wq, const float* __restrict__ wk,
                            const float* __restrict__ wv, const float* __restrict__ wo,
                            const float* __restrict__ w1, const float* __restrict__ w2,
                            const float* __restrict__ bq, const float* __restrict__ bk,
                            const float* __restrict__ bv,
                            const float* __restrict__ g1, const float* __restrict__ b1,
                            const float* __restrict__ m1, const float* __restrict__ v1,
                            const float* __restrict__ g2, const float* __restrict__ b2,
                            const float* __restrict__ m2, const float* __restrict__ v2,
                            u16* __restrict__ h,
                            u16* __restrict__ wqkvT, u16* __restrict__ woT,
                            u16* __restrict__ w1T, u16* __restrict__ w2T,
                            float* __restrict__ bqkv,
                            float* __restrict__ bn2sc, float* __restrict__ bn2sh) {
    int bid = blockIdx.x;
    if (bid < 2048) {                         // bn1 part
        int idx = bid * 256 + threadIdx.x;
        int base = idx * 4;
        int c = base & 255;
        float4 xv = *(const float4*)(x + base);
        ushort4 pk;
        {
            float sc0 = g1[c] * rsqrtf(v1[c] + EPS);
            pk.x = f2bf(fmaf(xv.x, sc0, b1[c] - m1[c] * sc0));
            float sc1 = g1[c+1] * rsqrtf(v1[c+1] + EPS);
            pk.y = f2bf(fmaf(xv.y, sc1, b1[c+1] - m1[c+1] * sc1));
            float sc2 = g1[c+2] * rsqrtf(v1[c+2] + EPS);
            pk.z = f2bf(fmaf(xv.z, sc2, b1[c+2] - m1[c+2] * sc2));
            float sc3 = g1[c+3] * rsqrtf(v1[c+3] + EPS);
            pk.w = f2bf(fmaf(xv.w, sc3, b1[c+3] - m1[c+3] * sc3));
        }
        *(ushort4*)(h + base) = pk;
        return;
    }
    int idx = (bid - 2048) * 256 + threadIdx.x;
    if (idx < 196608) {                       // wqkvT [768][256]
        int sec = idx >> 16;                  // 0=q, 1=k, 2=v
        int i = idx & 65535;
        int k = i >> 8, n = i & 255;
        const float* w = sec == 0 ? wq : (sec == 1 ? wk : wv);
        float v = w[i];                       // coalesced: w[k*256+n]
        if (sec == 1) v *= C1F;
        wqkvT[(sec * 256 + n) * 256 + k] = f2bf(v);
    } else if (idx < 262144) {                // woT [256][256]
        int i = idx - 196608; int k = i >> 8, n = i & 255;
        woT[n * 256 + k] = f2bf(wo[i]);
    } else if (idx < 524288) {                // w1T [1024][256]
        int i = idx - 262144; int k = i >> 10, n = i & 1023;
        w1T[n * 256 + k] = f2bf(w1[i]);
    } else if (idx < 786432) {                // w2T [256][1024]
        int i = idx - 524288; int k = i >> 8, n = i & 255;
        w2T[n * 1024 + k] = f2bf(w2[i]);
    } else if (idx < 787200) {                // bqkv [768]
        int i = idx - 786432;
        bqkv[i] = (i < 256) ? bq[i] : (i < 512 ? bk[i - 256] * C1F : bv[i - 512]);
    } else if (idx < 787456) {                // bn2 sc/sh
        int i = idx - 787200;
        float sc = g2[i] * rsqrtf(v2[i] + EPS);
        bn2sc[i] = sc; bn2sh[i] = b2[i] - m2[i] * sc;
    }
}

// ---------------------------------------------------------------------------
// 64x128-tile double-buffered GEMM (QKV, FFN1). Wave = 32 rows x 64 cols
// (w&1 = row half, w>>1 = col half). 48 KB LDS.
// EPI 0: qkv (col<512: +bias->row-major qkb; col>=512: +bias->vT transposed)
// EPI 2: gelu->bf16
// ---------------------------------------------------------------------------
template <int EPI>
__global__ __launch_bounds__(256) void gemm128(
        const u16* __restrict__ A, const u16* __restrict__ Bt,
        int M, int N, int K,
        const float* __restrict__ bias, u16* __restrict__ out_bf,
        u16* __restrict__ out_vt) {
    __shared__ u16 abuf[2][4096];    // 64 x 64k
    __shared__ u16 bbuf[2][8192];    // 128 x 64k
    const int t = threadIdx.x;
    const int w = t >> 6, lane = t & 63;
    const int l = lane & 15, Q = lane >> 4;
    const int m0 = blockIdx.x * 64;
    const int n0 = blockIdx.y * 128;
    const int rh = (w & 1) * 32;
    const int ch = (w >> 1) * 64;

    f32x4 acc[2][4];
#pragma unroll
    for (int mt = 0; mt < 2; ++mt)
#pragma unroll
        for (int nt = 0; nt < 4; ++nt) acc[mt][nt] = (f32x4){0.f, 0.f, 0.f, 0.f};

    auto stage = [&](int k0, int b) {
#pragma unroll
        for (int j = 0; j < 2; ++j) {
            int idx = j * 256 + t;
            int r = idx >> 3, c8 = idx & 7;
            int sc = c8 ^ (r & 7);
            async_cp16(A + (size_t)(m0 + r) * K + k0 + sc * 8, abuf[b] + idx * 8);
        }
#pragma unroll
        for (int j = 0; j < 4; ++j) {
            int idx = j * 256 + t;
            int r = idx >> 3, c8 = idx & 7;
            int sc = c8 ^ (r & 7);
            async_cp16(Bt + (size_t)(n0 + r) * K + k0 + sc * 8, bbuf[b] + idx * 8);
        }
    };

    const int nit = K >> 6;
    stage(0, 0);
    for (int i = 0; i < nit; ++i) {
        __syncthreads();              // vmcnt drained: tile i ready
        if (i + 1 < nit) stage((i + 1) << 6, (i + 1) & 1);
        const u16* ab = abuf[i & 1];
        const u16* bb = bbuf[i & 1];
#pragma unroll
        for (int kd = 0; kd < 2; ++kd) {
            short8 afr[2], bfr[4];
#pragma unroll
            for (int mt = 0; mt < 2; ++mt) {
                int ar = rh + mt * 16 + l;
                afr[mt] = *(const short8*)(ab + ar * 64 + (((kd * 4 + Q) ^ (ar & 7))) * 8);
            }
#pragma unroll
            for (int nt = 0; nt < 4; ++nt) {
                int br = ch + nt * 16 + l;
                bfr[nt] = *(const short8*)(bb + br * 64 + (((kd * 4 + Q) ^ (br & 7))) * 8);
            }
#pragma unroll
            for (int mt = 0; mt < 2; ++mt)
#pragma unroll
                for (int nt = 0; nt < 4; ++nt)
                    acc[mt][nt] = __builtin_amdgcn_mfma_f32_16x16x32_bf16(afr[mt], bfr[nt], acc[mt][nt], 0, 0, 0);
        }
    }

#pragma unroll
    for (int mt = 0; mt < 2; ++mt)
#pragma unroll
        for (int nt = 0; nt < 4; ++nt) {
            int col = n0 + ch + nt * 16 + l;
            int row0 = m0 + rh + mt * 16 + Q * 4;
            if (EPI == 0) {
                float b = bias[col];
                if (col < 512) {
#pragma unroll
                    for (int r = 0; r < 4; ++r)
                        out_bf[(size_t)(row0 + r) * 512 + col] = f2bf(acc[mt][nt][r] + b);
                } else {
                    ushort4 pk;
                    pk.x = f2bf(acc[mt][nt][0] + b);
                    pk.y = f2bf(acc[mt][nt][1] + b);
                    pk.z = f2bf(acc[mt][nt][2] + b);
                    pk.w = f2bf(acc[mt][nt][3] + b);
                    *(ushort4*)(out_vt + (size_t)(col - 512) * 8192 + row0) = pk;
                }
            } else {
#pragma unroll
                for (int r = 0; r < 4; ++r) {
                    float val = acc[mt][nt][r];
                    float gl = 0.5f * val * (1.f + erff(val * 0.70710678118654752f));
                    out_bf[(size_t)(row0 + r) * N + col] = f2bf(gl);
                }
            }
        }
}

// ---------------------------------------------------------------------------
// 64x64-tile double-buffered GEMM (kept for FFN2). EPI 3: +resid->f32
// ---------------------------------------------------------------------------
__global__ __launch_bounds__(256) void gemm64_res(
        const u16* __restrict__ A, const u16* __restrict__ Bt,
        int M, int N, int K,
        const float* __restrict__ resid, float* __restrict__ out_f32) {
    __shared__ u16 abuf[2][4096];
    __shared__ u16 bbuf[2][4096];
    const int t = threadIdx.x;
    const int w = t >> 6, lane = t & 63;
    const int l = lane & 15, Q = lane >> 4;
    const int m0 = blockIdx.x * 64;
    const int n0 = blockIdx.y * 64;

    f32x4 acc[4];
#pragma unroll
    for (int nt = 0; nt < 4; ++nt) acc[nt] = (f32x4){0.f, 0.f, 0.f, 0.f};

    auto stage = [&](int k0, int b) {
#pragma unroll
        for (int j = 0; j < 2; ++j) {
            int idx = j * 256 + t;
            int r = idx >> 3, c8 = idx & 7;
            int sc = c8 ^ (r & 7);
            async_cp16(A + (size_t)(m0 + r) * K + k0 + sc * 8, abuf[b] + idx * 8);
        }
#pragma unroll
        for (int j = 0; j < 2; ++j) {
            int idx = j * 256 + t;
            int r = idx >> 3, c8 = idx & 7;
            int sc = c8 ^ (r & 7);
            async_cp16(Bt + (size_t)(n0 + r) * K + k0 + sc * 8, bbuf[b] + idx * 8);
        }
    };

    const int nit = K >> 6;
    stage(0, 0);
    for (int i = 0; i < nit; ++i) {
        __syncthreads();
        if (i + 1 < nit) stage((i + 1) << 6, (i + 1) & 1);
        const u16* ab = abuf[i & 1];
        const u16* bb = bbuf[i & 1];
#pragma unroll
        for (int kd = 0; kd < 2; ++kd) {
            int ar = w * 16 + l;
            short8 afr = *(const short8*)(ab + ar * 64 + (((kd * 4 + Q) ^ (ar & 7))) * 8);
#pragma unroll
            for (int nt = 0; nt < 4; ++nt) {
                int r = nt * 16 + l;
                short8 bfr = *(const short8*)(bb + r * 64 + (((kd * 4 + Q) ^ (r & 7))) * 8);
                acc[nt] = __builtin_amdgcn_mfma_f32_16x16x32_bf16(afr, bfr, acc[nt], 0, 0, 0);
            }
        }
    }

#pragma unroll
    for (int nt = 0; nt < 4; ++nt) {
        int col = n0 + nt * 16 + l;
        int row0 = m0 + w * 16 + Q * 4;
#pragma unroll
        for (int r = 0; r < 4; ++r) {
            size_t oidx = (size_t)(row0 + r) * N + col;
            out_f32[oidx] = acc[nt][r] + resid[oidx];
        }
    }
}

// ---------------------------------------------------------------------------
// O-proj with FUSED combine (unchanged from R13).
// ---------------------------------------------------------------------------
__global__ __launch_bounds__(256) void gemm_oproj(
        const u16* __restrict__ opart, const float* __restrict__ lpart,
        const u16* __restrict__ Bt,
        const float* __restrict__ bias, const float* __restrict__ resid,
        float* __restrict__ out_f32, u16* __restrict__ out_bf,
        const float* __restrict__ b2sc, const float* __restrict__ b2sh) {
    __shared__ u16 abuf[4096];        // single-buffered combined-A (8 KB)
    __shared__ u16 bbuf[2][4096];
    const int t = threadIdx.x;
    const int w = t >> 6, lane = t & 63;
    const int l = lane & 15, Q = lane >> 4;
    const int m0 = blockIdx.x * 64;
    const int n0 = blockIdx.y * 64;
    const size_t SPSTR = (size_t)16 * 2048 * 64;   // opart sp stride (elems)

    f32x4 acc[4];
#pragma unroll
    for (int nt = 0; nt < 4; ++nt) acc[nt] = (f32x4){0.f, 0.f, 0.f, 0.f};

    auto stageB = [&](int k0, int b) {
#pragma unroll
        for (int j = 0; j < 2; ++j) {
            int idx = j * 256 + t;
            int r = idx >> 3, c8 = idx & 7;
            int sc = c8 ^ (r & 7);
            async_cp16(Bt + (size_t)(n0 + r) * 256 + k0 + sc * 8, bbuf[b] + idx * 8);
        }
    };

    stageB(0, 0);
    for (int i = 0; i < 4; ++i) {     // k0 = i*64, head hd = i
        uint4 aw[2];
#pragma unroll
        for (int j = 0; j < 2; ++j) {
            int idx = j * 256 + t;
            int r = idx >> 3, c8 = idx & 7;
            int dc = c8 ^ (r & 7);            // global d-chunk stored in this slot
            int row = m0 + r;
            int bh = (row >> 11) * 4 + i;
            int q = row & 2047;
            size_t lb = (size_t)bh * 2048 + q;
            float ls = lpart[lb] + lpart[lb + 32768] + lpart[lb + 65536] + lpart[lb + 98304];
            float inv = 1.0f / ls;
            size_t base = ((size_t)bh * 2048 + q) * 64 + dc * 8;
            uint4 v0 = *(const uint4*)(opart + base);
            uint4 v1 = *(const uint4*)(opart + SPSTR + base);
            uint4 v2 = *(const uint4*)(opart + 2 * SPSTR + base);
            uint4 v3 = *(const uint4*)(opart + 3 * SPSTR + base);
            u32 o[4];
            const u32* p0 = &v0.x; const u32* p1 = &v1.x;
            const u32* p2 = &v2.x; const u32* p3 = &v3.x;
#pragma unroll
            for (int e = 0; e < 4; ++e) {
                float lo = __uint_as_float(p0[e] << 16) + __uint_as_float(p1[e] << 16)
                         + __uint_as_float(p2[e] << 16) + __uint_as_float(p3[e] << 16);
                float hi = __uint_as_float(p0[e] & 0xffff0000u) + __uint_as_float(p1[e] & 0xffff0000u)
                         + __uint_as_float(p2[e] & 0xffff0000u) + __uint_as_float(p3[e] & 0xffff0000u);
                o[e] = (u32)f2bf(lo * inv) | ((u32)f2bf(hi * inv) << 16);
            }
            aw[j] = make_uint4(o[0], o[1], o[2], o[3]);
        }
        __syncthreads();              // prev compute done reading abuf; B[i] drained
#pragma unroll
        for (int j = 0; j < 2; ++j)
            *(uint4*)(abuf + ((size_t)(j * 256 + t)) * 8) = aw[j];
        if (i < 3) stageB((i + 1) * 64, (i + 1) & 1);
        __syncthreads();              // abuf visible to all waves
        const u16* bb = bbuf[i & 1];
#pragma unroll
        for (int kd = 0; kd < 2; ++kd) {
            int ar = w * 16 + l;
            short8 afr = *(const short8*)(abuf + ar * 64 + (((kd * 4 + Q) ^ (ar & 7))) * 8);
#pragma unroll
            for (int nt = 0; nt < 4; ++nt) {
                int r = nt * 16 + l;
                short8 bfr = *(const short8*)(bb + r * 64 + (((kd * 4 + Q) ^ (r & 7))) * 8);
                acc[nt] = __builtin_amdgcn_mfma_f32_16x16x32_bf16(afr, bfr, acc[nt], 0, 0, 0);
            }
        }
    }

#pragma unroll
    for (int nt = 0; nt < 4; ++nt) {
        int col = n0 + nt * 16 + l;
        int row0 = m0 + w * 16 + Q * 4;
#pragma unroll
        for (int r = 0; r < 4; ++r) {
            size_t oidx = (size_t)(row0 + r) * 256 + col;
            float val = acc[nt][r] + bias[col] + resid[oidx];
            out_f32[oidx] = val;
            out_bf[oidx] = f2bf(fmaf(val, b2sc[col], b2sh[col]));
        }
    }
}

// ---------------------------------------------------------------------------
// Flash attention v10: WG = 128 q rows (qt 0..15), wave = 32 rows as TWO
// 16-row accumulator groups. Each K/V ds_read now feeds 2 MFMAs -> LDS read
// volume halves (1.07 GB -> 0.54 GB total; LDS was the binding pipe at
// ~15.5 us vs ~3.6 us MFMA). K/V LDS double-buffered (32 KB, m97 single-
// barrier-per-iter structure) since occupancy drops 8->4 WG/CU and intra-
// block prefetch must hide the stage latency now. Grid = 1024 = qt*64 +
// sp*16 + bh (64 % 8 == 0 preserves per-XCD K/V L2 reuse). l via ones-MFMA.
// ---------------------------------------------------------------------------
static __device__ __forceinline__ void stage_tiles(const u16* kglob, const u16* vglob,
                                                   u16* kdst, u16* vdst,
                                                   int w, int lane, int kt) {
#pragma unroll
    for (int j = 0; j < 2; ++j) {
        int cw = (w * 2 + j) * 64 + lane;     // chunk 0..511
        int r = cw >> 3;                       // tile row 0..63
        int c = (cw & 7) ^ (r & 7);            // swizzled source chunk
        async_cp16(kglob + ((size_t)(kt * 64 + r)) * 512 + c * 8, kdst + (w * 2 + j) * 512);
        async_cp16(vglob + ((size_t)r) * 8192 + kt * 64 + c * 8, vdst + (w * 2 + j) * 512);
    }
}

__global__ __launch_bounds__(256) void attn_kernel(const u16* __restrict__ qk,
                                                   const u16* __restrict__ vT,
                                                   u16* __restrict__ opart,
                                                   float* __restrict__ lpart) {
    __shared__ u16 kbuf[2][4096];
    __shared__ u16 vbuf[2][4096];
    const int t = threadIdx.x;
    const int w = t >> 6, lane = t & 63;
    const int l = lane & 15, Q = lane >> 4;
    const int blk = blockIdx.x;
    const int qt = blk >> 6;          // 0..15  (slowest: XCD-local K/V reuse)
    const int sp = (blk >> 4) & 3;    // 0..3   (512 s each)
    const int bh = blk & 15;          // 0..15
    const int bb = bh >> 2, hd = bh & 3;
    const size_t rowbase = (size_t)bb * 2048;
    const int q0 = qt * 128 + w * 32;  // wave covers q0..q0+31 (2 groups of 16)

    short8 qf[2][2];
#pragma unroll
    for (int g = 0; g < 2; ++g)
#pragma unroll
        for (int kd = 0; kd < 2; ++kd)
            qf[g][kd] = *(const short8*)(qk + (rowbase + q0 + g * 16 + l) * 512
                                         + hd * 64 + kd * 32 + Q * 8);

    f32x4 o[2][4];
#pragma unroll
    for (int g = 0; g < 2; ++g)
#pragma unroll
        for (int dt = 0; dt < 4; ++dt) o[g][dt] = (f32x4){0.f, 0.f, 0.f, 0.f};
    f32x4 oL[2];
    oL[0] = (f32x4){0.f, 0.f, 0.f, 0.f};
    oL[1] = (f32x4){0.f, 0.f, 0.f, 0.f};
    union { u32 u[2]; short4v s4; } ones;
    ones.u[0] = 0x3F803F80u; ones.u[1] = 0x3F803F80u;   // bf16 1.0 x4

    const u16* kglob = qk + (rowbase + sp * 512) * 512 + 256 + hd * 64;
    const u16* vglob = vT + ((size_t)(hd * 64)) * 8192 + rowbase + sp * 512;

    stage_tiles(kglob, vglob, kbuf[0], vbuf[0], w, lane, 0);
    for (int kt = 0; kt < 8; ++kt) {
        __syncthreads();              // drains vmcnt: tile kt ready; buf[kt^1] free
        if (kt + 1 < 8)
            stage_tiles(kglob, vglob, kbuf[(kt + 1) & 1], vbuf[(kt + 1) & 1],
                        w, lane, kt + 1);
        const u16* kb = kbuf[kt & 1];
        const u16* vb = vbuf[kt & 1];

        union { u32 u[2]; short4v s4; } pf[2][4];
#pragma unroll
        for (int st = 0; st < 4; ++st) {
            int r = st * 16 + l;
            short8 kf0 = *(const short8*)(kb + r * 64 + ((Q) ^ (r & 7)) * 8);
            short8 kf1 = *(const short8*)(kb + r * 64 + ((4 + Q) ^ (r & 7)) * 8);
#pragma unroll
            for (int g = 0; g < 2; ++g) {
                f32x4 s = (f32x4){0.f, 0.f, 0.f, 0.f};
                s = __builtin_amdgcn_mfma_f32_16x16x32_bf16(kf0, qf[g][0], s, 0, 0, 0);
                s = __builtin_amdgcn_mfma_f32_16x16x32_bf16(kf1, qf[g][1], s, 0, 0, 0);
                float p0 = EXP2F(s[0]);
                float p1 = EXP2F(s[1]);
                float p2 = EXP2F(s[2]);
                float p3 = EXP2F(s[3]);
                pf[g][st].u[0] = pack_bf2_trunc(p0, p1);
                pf[g][st].u[1] = pack_bf2_trunc(p2, p3);
            }
        }

#pragma unroll
        for (int c = 0; c < 4; ++c) {
#pragma unroll
            for (int dt = 0; dt < 4; ++dt) {
                int r = dt * 16 + l;
                int slot = (2 * c + (Q >> 1)) ^ (r & 7);
                short4v vf = *(const short4v*)(vb + r * 64 + slot * 8 + (Q & 1) * 4);
                o[0][dt] = MFMA16(vf, pf[0][c].s4, o[0][dt]);
                o[1][dt] = MFMA16(vf, pf[1][c].s4, o[1][dt]);
            }
            oL[0] = MFMA16(ones.s4, pf[0][c].s4, oL[0]);
            oL[1] = MFMA16(ones.s4, pf[1][c].s4, oL[1]);
        }
    }

    // epilogue: bf16 partials; l = oL[g][0] (each col q holds its sum)
#pragma unroll
    for (int g = 0; g < 2; ++g) {
        u16* ob = opart + (((size_t)sp * 16 + bh) * 2048 + q0 + g * 16) * 64;
#pragma unroll
        for (int dt = 0; dt < 4; ++dt) {
            ushort4 pk;
            pk.x = f2bf(o[g][dt][0]);
            pk.y = f2bf(o[g][dt][1]);
            pk.z = f2bf(o[g][dt][2]);
            pk.w = f2bf(o[g][dt][3]);
            *(ushort4*)(ob + (size_t)l * 64 + dt * 16 + Q * 4) = pk;
        }
        if (Q == 0) {
            size_t lb = ((size_t)sp * 16 + bh) * 2048 + q0 + g * 16;
            lpart[lb + l] = oL[g][0];
        }
    }
}

// ---------------------------------------------------------------------------
extern "C" void kernel_launch(void* const* d_in, const int* in_sizes, int n_in,
                              void* d_out, int out_size, void* d_ws, size_t ws_size,
                              hipStream_t stream) {
    (void)in_sizes; (void)n_in; (void)out_size; (void)ws_size;
    const float* x  = (const float*)d_in[0];
    const float* g1 = (const float*)d_in[1];
    const float* b1 = (const float*)d_in[2];
    const float* m1 = (const float*)d_in[3];
    const float* v1 = (const float*)d_in[4];
    const float* wq = (const float*)d_in[5];
    const float* bq = (const float*)d_in[6];
    const float* wk = (const float*)d_in[7];
    const float* bk = (const float*)d_in[8];
    const float* wv = (const float*)d_in[9];
    const float* bv = (const float*)d_in[10];
    const float* wo = (const float*)d_in[11];
    const float* bo = (const float*)d_in[12];
    const float* g2 = (const float*)d_in[13];
    const float* b2 = (const float*)d_in[14];
    const float* m2 = (const float*)d_in[15];
    const float* v2 = (const float*)d_in[16];
    const float* w1 = (const float*)d_in[17];
    const float* w2 = (const float*)d_in[18];

    char* ws = (char*)d_ws;
    u16*   qkb    = (u16*)(ws + (0ull << 20));    // [8192][512] bf16, 8 MB
    u16*   vTb    = (u16*)(ws + (8ull << 20));    // [256][8192] bf16, 4 MB
    u16*   h_buf  = (u16*)(ws + (12ull << 20));   // [8192][256] bf16, 4 MB
    float* x1     = (float*)(ws + (20ull << 20)); // [8192][256] f32, 8 MB
    u16*   h2     = (u16*)(ws + (28ull << 20));   // [8192][256] bf16, 4 MB
    u16*   gbuf   = (u16*)(ws + (32ull << 20));   // [8192][1024] bf16, 16 MB
    u16*   opart  = (u16*)(ws + (48ull << 20));   // [4][16][2048][64] bf16, 16 MB
    float* lpart  = (float*)(ws + (80ull << 20)); // [4][16][2048] f32, 512 KB
    u16*   wqkvT  = (u16*)(ws + (81ull << 20));   // [768][256] bf16
    u16*   woT    = (u16*)(ws + (82ull << 20));   // [256][256]
    u16*   w1T    = (u16*)(ws + (83ull << 20));   // [1024][256]
    u16*   w2T    = (u16*)(ws + (84ull << 20));   // [256][1024]
    float* bqkv   = (float*)(ws + (85ull << 20)); // [768]
    float* bn2sc  = (float*)(ws + (85ull << 20) + 4096);
    float* bn2sh  = (float*)(ws + (85ull << 20) + 8192);
    float* out    = (float*)d_out;

    prep_bn1_kernel<<<5125, 256, 0, stream>>>(x, wq, wk, wv, wo, w1, w2, bq, bk, bv,
                                              g1, b1, m1, v1, g2, b2, m2, v2,
                                              h_buf, wqkvT, woT, w1T, w2T, bqkv,
                                              bn2sc, bn2sh);
    // QKV projection, 64x128 tiles (q|k row-major into qkb; v transposed into vTb)
    gemm128<0><<<dim3(128, 6), 256, 0, stream>>>(
        h_buf, wqkvT, 8192, 768, 256, bqkv, qkb, vTb);
    // attention partials (1D grid, qt slowest for XCD L2 reuse; 128 q/WG,
    // 2 q-groups per wave, double-buffered K/V LDS)
    attn_kernel<<<1024, 256, 0, stream>>>(qkb, vTb, opart, lpart);
    // O projection with fused combine + residual + bn2
    gemm_oproj<<<dim3(128, 4), 256, 0, stream>>>(
        opart, lpart, woT, bo, x, x1, h2, bn2sc, bn2sh);
    // FFN1 + gelu, 64x128 tiles
    gemm128<2><<<dim3(128, 8), 256, 0, stream>>>(
        h2, w1T, 8192, 1024, 256, bqkv, gbuf, nullptr);
    // FFN2 + residual -> out
    gemm64_res<<<dim3(128, 4), 256, 0, stream>>>(
        gbuf, w2T, 8192, 256, 1024, x1, out);
}